// Round 6
// baseline (1164.856 us; speedup 1.0000x reference)
//
#include <hip/hip_runtime.h>

#define N 32
#define C 512
#define HW 4096
#define CB 32
#define CCH 16        // channels per slab block
#define NCHUNK 32     // C / CCH
#define EPS 1e-5f
#define NBLK 1024u    // 32 n * 32 chunks; 4 blocks/CU exact fit

typedef float fvec4 __attribute__((ext_vector_type(4)));

// Device-scope generation barrier. All NBLK blocks must be co-resident
// (guaranteed by exact-fit occupancy: launch_bounds(256,4), 16.9KB LDS).
// Release: fetch_add(cnt) ACQ_REL publishes this block's prior stores.
// The last arriver resets cnt (relaxed) then bumps gen (release); waiters
// acquire-load gen -> transitive happens-before covers all blocks' writes.
// __threadfence() on both sides forces L2 writeback/invalidate (per-XCD L2
// is not cross-coherent; Infinity Cache is the agent coherence point).
__device__ __forceinline__ void grid_barrier(unsigned* cnt, unsigned* gen)
{
    __syncthreads();
    if (threadIdx.x == 0) {
        const unsigned g =
            __hip_atomic_load(gen, __ATOMIC_ACQUIRE, __HIP_MEMORY_SCOPE_AGENT);
        __threadfence();
        const unsigned a = __hip_atomic_fetch_add(
            cnt, 1u, __ATOMIC_ACQ_REL, __HIP_MEMORY_SCOPE_AGENT);
        if (a == NBLK - 1u) {
            __hip_atomic_store(cnt, 0u, __ATOMIC_RELAXED,
                               __HIP_MEMORY_SCOPE_AGENT);
            __hip_atomic_fetch_add(gen, 1u, __ATOMIC_RELEASE,
                                   __HIP_MEMORY_SCOPE_AGENT);
        } else {
            while (__hip_atomic_load(gen, __ATOMIC_ACQUIRE,
                                     __HIP_MEMORY_SCOPE_AGENT) == g)
                __builtin_amdgcn_s_sleep(2);
        }
        __threadfence();
    }
    __syncthreads();
}

// Single persistent kernel, 5 phases separated by grid_barrier.
// Block b owns slab (n = b>>5, channels c0..c0+15) in phases 1/3/5.
// x is streamed fwd (ph1), reverse (ph3, L3-LRU-warm), fwd (ph5, NT stores).
__global__ __launch_bounds__(256, 4) void fused(
    const float* __restrict__ x, const float* __restrict__ wk_w,
    const float* __restrict__ wk_b, const float* __restrict__ wv1_w,
    const float* __restrict__ ln_g, const float* __restrict__ ln_b,
    const float* __restrict__ wv2_w, float* __restrict__ out,
    float* __restrict__ partial, float* __restrict__ attn,
    float* __restrict__ ctx, float* __restrict__ ovec,
    unsigned* __restrict__ bar)
{
    __shared__ float smem[4224];  // ph2: l[4096]+m[64]+inv[64]; ph3: red; ph4: ctx+v
    unsigned* cnt = bar;
    unsigned* gen = bar + 1;
    const int tid   = threadIdx.x;
    const int b     = blockIdx.x;
    const int n     = b >> 5;
    const int chunk = b & 31;
    const int c0    = chunk * CCH;
    const float4* xb = (const float4*)(x + ((size_t)n * C + c0) * HW);

    // ---- Phase 1: logit partials; stream slab forward ----
    {
        float4 acc[4];
        #pragma unroll
        for (int i = 0; i < 4; ++i) acc[i] = make_float4(0.f, 0.f, 0.f, 0.f);
        #pragma unroll 4
        for (int c = 0; c < CCH; ++c) {
            const float wv = wk_w[c0 + c];
            #pragma unroll
            for (int i = 0; i < 4; ++i) {
                const float4 xv = xb[c * 1024 + i * 256 + tid];
                acc[i].x += xv.x * wv; acc[i].y += xv.y * wv;
                acc[i].z += xv.z * wv; acc[i].w += xv.w * wv;
            }
        }
        float4* pb = (float4*)(partial + ((size_t)n * NCHUNK + chunk) * HW);
        #pragma unroll
        for (int i = 0; i < 4; ++i) pb[i * 256 + tid] = acc[i];
    }
    grid_barrier(cnt, gen);

    // ---- Phase 2: softmax over H per (n,w); blocks 0..31, one n each ----
    if (b < N) {
        float* l_s  = smem;          // 4096 logits, layout h*64+w
        float* m_s  = smem + 4096;   // 64 per-w max
        float* is_s = smem + 4160;   // 64 per-w 1/sum
        const float bias = wk_b[0];
        for (int i4 = tid; i4 < 1024; i4 += 256) {
            float4 sum = make_float4(bias, bias, bias, bias);
            for (int ch = 0; ch < NCHUNK; ++ch) {
                const float4 p = ((const float4*)(partial +
                    ((size_t)b * NCHUNK + ch) * HW))[i4];
                sum.x += p.x; sum.y += p.y; sum.z += p.z; sum.w += p.w;
            }
            ((float4*)l_s)[i4] = sum;
        }
        __syncthreads();
        if (tid < 64) {              // w = tid; reduce over h
            float m = -1e30f;
            for (int h = 0; h < 64; ++h) m = fmaxf(m, l_s[h * 64 + tid]);
            float s = 0.f;
            for (int h = 0; h < 64; ++h) s += __expf(l_s[h * 64 + tid] - m);
            m_s[tid] = m; is_s[tid] = 1.f / s;
        }
        __syncthreads();
        for (int idx = tid; idx < HW; idx += 256) {
            const int w = idx & 63;
            attn[(size_t)b * HW + idx] = __expf(l_s[idx] - m_s[w]) * is_s[w];
        }
    }
    grid_barrier(cnt, gen);

    // ---- Phase 3: ctx; stream slab in REVERSE (L3 tail is LRU-warm) ----
    {
        const float4* ar = (const float4*)(attn + (size_t)n * HW);
        float4 av[4];
        #pragma unroll
        for (int i = 0; i < 4; ++i) av[i] = ar[i * 256 + tid];
        float s[CCH];
        #pragma unroll
        for (int c = 0; c < CCH; ++c) s[c] = 0.f;
        #pragma unroll 4
        for (int c = CCH - 1; c >= 0; --c) {
            float t = 0.f;
            #pragma unroll
            for (int i = 0; i < 4; ++i) {
                const float4 xv = xb[c * 1024 + i * 256 + tid];
                t += xv.x * av[i].x + xv.y * av[i].y
                   + xv.z * av[i].z + xv.w * av[i].w;
            }
            s[c] = t;
        }
        const int lane = tid & 63, wv = tid >> 6;
        #pragma unroll
        for (int c = 0; c < CCH; ++c) {
            float t = s[c];
            #pragma unroll
            for (int o = 32; o > 0; o >>= 1) t += __shfl_xor(t, o);
            if (lane == 0) smem[c * 4 + wv] = t;
        }
        __syncthreads();
        if (tid < CCH) {
            ctx[(size_t)n * C + c0 + tid] = smem[tid * 4] + smem[tid * 4 + 1]
                                          + smem[tid * 4 + 2] + smem[tid * 4 + 3];
        }
    }
    grid_barrier(cnt, gen);

    // ---- Phase 4: bottleneck MLP + LayerNorm; blocks 0..31, one n each ----
    if (b < N) {
        float* ctx_s = smem;         // 512
        float* v_s   = smem + 512;   // 32
        ctx_s[tid]       = ctx[b * C + tid];
        ctx_s[tid + 256] = ctx[b * C + tid + 256];
        __syncthreads();
        {   // 8 lanes per bottleneck channel
            const int bb = tid >> 3, sub = tid & 7;
            const float* wr = wv1_w + bb * C;
            float s = 0.f;
            #pragma unroll 8
            for (int j = sub; j < C; j += 8) s += wr[j] * ctx_s[j];
            #pragma unroll
            for (int o = 4; o > 0; o >>= 1) s += __shfl_down(s, o, 8);
            if (sub == 0) v_s[bb] = s;
        }
        __syncthreads();
        if (tid < CB) {
            const float val = v_s[tid];
            float sm = val, sq = val * val;
            #pragma unroll
            for (int o = 16; o > 0; o >>= 1) {
                sm += __shfl_xor(sm, o, 32);
                sq += __shfl_xor(sq, o, 32);
            }
            const float mu  = sm / CB;
            const float var = sq / CB - mu * mu;
            const float vh  = (val - mu) * rsqrtf(var + EPS) * ln_g[tid] + ln_b[tid];
            v_s[tid] = fmaxf(vh, 0.f);
        }
        __syncthreads();
        for (int c = tid; c < C; c += 256) {
            const float* w2 = wv2_w + c * CB;
            float a = 0.f;
            #pragma unroll
            for (int bq = 0; bq < CB; ++bq) a += v_s[bq] * w2[bq];
            ovec[b * C + c] = a;
        }
    }
    grid_barrier(cnt, gen);

    // ---- Phase 5: out = x + ovec; stream slab forward, NT stores ----
    {
        const fvec4* xp = (const fvec4*)x   + ((size_t)n * C + c0) * 1024;
        fvec4*       op = (fvec4*)out       + ((size_t)n * C + c0) * 1024;
        #pragma unroll 4
        for (int c = 0; c < CCH; ++c) {
            const float a = ovec[n * C + c0 + c];
            #pragma unroll
            for (int i = 0; i < 4; ++i) {
                const int idx = c * 1024 + i * 256 + tid;
                fvec4 v = xp[idx];
                v += a;
                __builtin_nontemporal_store(v, op + idx);
            }
        }
    }
}

extern "C" void kernel_launch(void* const* d_in, const int* in_sizes, int n_in,
                              void* d_out, int out_size, void* d_ws, size_t ws_size,
                              hipStream_t stream) {
    const float* x     = (const float*)d_in[0];
    const float* wk_w  = (const float*)d_in[1];
    const float* wk_b  = (const float*)d_in[2];
    const float* wv1_w = (const float*)d_in[3];
    const float* ln_g  = (const float*)d_in[4];
    const float* ln_b  = (const float*)d_in[5];
    const float* wv2_w = (const float*)d_in[6];
    float* out = (float*)d_out;

    float* ws      = (float*)d_ws;
    float* partial = ws;                                   // N*32*HW = 16 MiB
    float* attn    = partial + (size_t)N * NCHUNK * HW;    // N*HW
    float* ctx     = attn + (size_t)N * HW;                // N*C
    float* ovec    = ctx + (size_t)N * C;                  // N*C
    unsigned* bar  = (unsigned*)(ovec + (size_t)N * C);    // 2 x u32

    // zero the barrier (workspace is poisoned each iteration)
    hipMemsetAsync(bar, 0, 2 * sizeof(unsigned), stream);

    fused<<<NBLK, 256, 0, stream>>>(x, wk_w, wk_b, wv1_w, ln_g, ln_b, wv2_w,
                                    out, partial, attn, ctx, ovec, bar);
}

// Round 7
// 647.729 us; speedup vs baseline: 1.7984x; 1.7984x over previous
//
#include <hip/hip_runtime.h>

#define N 32
#define C 512
#define HW 4096
#define CB 32
#define CCH 16        // channels per slab block
#define NCHUNK 32     // C / CCH
#define EPS 1e-5f
#define NBLK 1024u    // 32 n * 32 chunks; 4 blocks/CU exact fit

typedef float fvec4 __attribute__((ext_vector_type(4)));

// Per-n sync primitives (thread 0 only, bracketed by __syncthreads outside).
// arrive: ACQ_REL RMW chains happens-before through the 32 arrivers, so the
// last arriver (prev==31) observes all 32 blocks' prior stores.
// wait_flag: relaxed poll (no cache-invalidate per iteration), then ONE
// acquire load to synchronize with set_flag's release.
__device__ __forceinline__ unsigned arrive(unsigned* ctr) {
    return __hip_atomic_fetch_add(ctr, 1u, __ATOMIC_ACQ_REL,
                                  __HIP_MEMORY_SCOPE_AGENT);
}
__device__ __forceinline__ void set_flag(unsigned* f) {
    __hip_atomic_store(f, 1u, __ATOMIC_RELEASE, __HIP_MEMORY_SCOPE_AGENT);
}
__device__ __forceinline__ void wait_flag(unsigned* f) {
    while (!__hip_atomic_load(f, __ATOMIC_RELAXED, __HIP_MEMORY_SCOPE_AGENT))
        __builtin_amdgcn_s_sleep(8);
    (void)__hip_atomic_load(f, __ATOMIC_ACQUIRE, __HIP_MEMORY_SCOPE_AGENT);
}

// Single fused kernel, NO grid-wide barriers: per-n counters/flags only.
// Block b owns slab (n = b>>5, channels c0..c0+15). x streamed fwd (P1),
// reverse (P3, L3-LRU-warm), fwd (P5, NT stores). Last P1-arriver of each n
// does that n's softmax; last P3-arriver does that n's MLP.
__global__ __launch_bounds__(256, 4) void fused(
    const float* __restrict__ x, const float* __restrict__ wk_w,
    const float* __restrict__ wk_b, const float* __restrict__ wv1_w,
    const float* __restrict__ ln_g, const float* __restrict__ ln_b,
    const float* __restrict__ wv2_w, float* __restrict__ out,
    float* __restrict__ partial, float* __restrict__ attn,
    float* __restrict__ ctx, float* __restrict__ ovec,
    unsigned* __restrict__ bar)
{
    __shared__ float smem[4224];   // P2: l[4096]+m[64]+inv[64]; P3: red; P4: ctx+v
    __shared__ unsigned role1, role2;
    const int tid   = threadIdx.x;
    const int b     = blockIdx.x;
    const int n     = b >> 5;
    const int chunk = b & 31;
    const int c0    = chunk * CCH;
    const float4* xb = (const float4*)(x + ((size_t)n * C + c0) * HW);
    unsigned* A  = bar + n * 64;        // arrival ctr, phase 1
    unsigned* F1 = bar + n * 64 + 16;   // attn-ready flag
    unsigned* B  = bar + n * 64 + 32;   // arrival ctr, phase 3
    unsigned* F2 = bar + n * 64 + 48;   // ovec-ready flag

    // ---- Phase 1: logit partials; stream slab forward ----
    {
        float4 acc[4];
        #pragma unroll
        for (int i = 0; i < 4; ++i) acc[i] = make_float4(0.f, 0.f, 0.f, 0.f);
        #pragma unroll 4
        for (int c = 0; c < CCH; ++c) {
            const float wv = wk_w[c0 + c];
            #pragma unroll
            for (int i = 0; i < 4; ++i) {
                const float4 xv = xb[c * 1024 + i * 256 + tid];
                acc[i].x += xv.x * wv; acc[i].y += xv.y * wv;
                acc[i].z += xv.z * wv; acc[i].w += xv.w * wv;
            }
        }
        float4* pb = (float4*)(partial + ((size_t)n * NCHUNK + chunk) * HW);
        #pragma unroll
        for (int i = 0; i < 4; ++i) pb[i * 256 + tid] = acc[i];
    }
    __syncthreads();
    if (tid == 0) role1 = (arrive(A) == NCHUNK - 1u);
    __syncthreads();

    // ---- Phase 2: last arriver of n does softmax over H per (n,w) ----
    if (role1) {
        float* l_s  = smem;          // 4096 logits, layout h*64+w
        float* m_s  = smem + 4096;   // 64 per-w max
        float* is_s = smem + 4160;   // 64 per-w 1/sum
        const float bias = wk_b[0];
        for (int i4 = tid; i4 < 1024; i4 += 256) {
            float4 sum = make_float4(bias, bias, bias, bias);
            for (int ch = 0; ch < NCHUNK; ++ch) {
                const float4 p = ((const float4*)(partial +
                    ((size_t)n * NCHUNK + ch) * HW))[i4];
                sum.x += p.x; sum.y += p.y; sum.z += p.z; sum.w += p.w;
            }
            ((float4*)l_s)[i4] = sum;
        }
        __syncthreads();
        if (tid < 64) {              // w = tid; reduce over h
            float m = -1e30f;
            for (int h = 0; h < 64; ++h) m = fmaxf(m, l_s[h * 64 + tid]);
            float s = 0.f;
            for (int h = 0; h < 64; ++h) s += __expf(l_s[h * 64 + tid] - m);
            m_s[tid] = m; is_s[tid] = 1.f / s;
        }
        __syncthreads();
        for (int idx = tid; idx < HW; idx += 256) {
            const int w = idx & 63;
            attn[(size_t)n * HW + idx] = __expf(l_s[idx] - m_s[w]) * is_s[w];
        }
    }
    __syncthreads();
    if (tid == 0) { if (role1) set_flag(F1); else wait_flag(F1); }
    __syncthreads();

    // ---- Phase 3: ctx; stream slab in REVERSE (L3 tail is LRU-warm) ----
    {
        const float4* ar = (const float4*)(attn + (size_t)n * HW);
        float4 av[4];
        #pragma unroll
        for (int i = 0; i < 4; ++i) av[i] = ar[i * 256 + tid];
        float s[CCH];
        #pragma unroll
        for (int c = 0; c < CCH; ++c) s[c] = 0.f;
        #pragma unroll 4
        for (int c = CCH - 1; c >= 0; --c) {
            float t = 0.f;
            #pragma unroll
            for (int i = 0; i < 4; ++i) {
                const float4 xv = xb[c * 1024 + i * 256 + tid];
                t += xv.x * av[i].x + xv.y * av[i].y
                   + xv.z * av[i].z + xv.w * av[i].w;
            }
            s[c] = t;
        }
        const int lane = tid & 63, wv = tid >> 6;
        #pragma unroll
        for (int c = 0; c < CCH; ++c) {
            float t = s[c];
            #pragma unroll
            for (int o = 32; o > 0; o >>= 1) t += __shfl_xor(t, o);
            if (lane == 0) smem[c * 4 + wv] = t;
        }
        __syncthreads();
        if (tid < CCH) {
            ctx[(size_t)n * C + c0 + tid] = smem[tid * 4] + smem[tid * 4 + 1]
                                          + smem[tid * 4 + 2] + smem[tid * 4 + 3];
        }
    }
    __syncthreads();
    if (tid == 0) role2 = (arrive(B) == NCHUNK - 1u);
    __syncthreads();

    // ---- Phase 4: last arriver of n does bottleneck MLP + LayerNorm ----
    if (role2) {
        float* ctx_s = smem;         // 512
        float* v_s   = smem + 512;   // 32
        ctx_s[tid]       = ctx[n * C + tid];
        ctx_s[tid + 256] = ctx[n * C + tid + 256];
        __syncthreads();
        {   // 8 lanes per bottleneck channel
            const int bb = tid >> 3, sub = tid & 7;
            const float* wr = wv1_w + bb * C;
            float s = 0.f;
            #pragma unroll 8
            for (int j = sub; j < C; j += 8) s += wr[j] * ctx_s[j];
            #pragma unroll
            for (int o = 4; o > 0; o >>= 1) s += __shfl_down(s, o, 8);
            if (sub == 0) v_s[bb] = s;
        }
        __syncthreads();
        if (tid < CB) {
            const float val = v_s[tid];
            float sm = val, sq = val * val;
            #pragma unroll
            for (int o = 16; o > 0; o >>= 1) {
                sm += __shfl_xor(sm, o, 32);
                sq += __shfl_xor(sq, o, 32);
            }
            const float mu  = sm / CB;
            const float var = sq / CB - mu * mu;
            const float vh  = (val - mu) * rsqrtf(var + EPS) * ln_g[tid] + ln_b[tid];
            v_s[tid] = fmaxf(vh, 0.f);
        }
        __syncthreads();
        for (int c = tid; c < C; c += 256) {
            const float* w2 = wv2_w + c * CB;
            float a = 0.f;
            #pragma unroll
            for (int bq = 0; bq < CB; ++bq) a += v_s[bq] * w2[bq];
            ovec[n * C + c] = a;
        }
    }
    __syncthreads();
    if (tid == 0) { if (role2) set_flag(F2); else wait_flag(F2); }
    __syncthreads();

    // ---- Phase 5: out = x + ovec; stream slab forward, NT stores ----
    {
        const fvec4* xp = (const fvec4*)x   + ((size_t)n * C + c0) * 1024;
        fvec4*       op = (fvec4*)out       + ((size_t)n * C + c0) * 1024;
        #pragma unroll 4
        for (int c = 0; c < CCH; ++c) {
            const float a = ovec[n * C + c0 + c];
            #pragma unroll
            for (int i = 0; i < 4; ++i) {
                const int idx = c * 1024 + i * 256 + tid;
                fvec4 v = xp[idx];
                v += a;
                __builtin_nontemporal_store(v, op + idx);
            }
        }
    }
}

extern "C" void kernel_launch(void* const* d_in, const int* in_sizes, int n_in,
                              void* d_out, int out_size, void* d_ws, size_t ws_size,
                              hipStream_t stream) {
    const float* x     = (const float*)d_in[0];
    const float* wk_w  = (const float*)d_in[1];
    const float* wk_b  = (const float*)d_in[2];
    const float* wv1_w = (const float*)d_in[3];
    const float* ln_g  = (const float*)d_in[4];
    const float* ln_b  = (const float*)d_in[5];
    const float* wv2_w = (const float*)d_in[6];
    float* out = (float*)d_out;

    float* ws      = (float*)d_ws;
    float* partial = ws;                                   // N*32*HW = 16 MiB
    float* attn    = partial + (size_t)N * NCHUNK * HW;    // N*HW
    float* ctx     = attn + (size_t)N * HW;                // N*C
    float* ovec    = ctx + (size_t)N * C;                  // N*C
    unsigned* bar  = (unsigned*)(ovec + (size_t)N * C);    // 32 n * 64 u32

    // zero the per-n counters/flags (workspace is poisoned each iteration)
    hipMemsetAsync(bar, 0, (size_t)N * 64 * sizeof(unsigned), stream);

    fused<<<NBLK, 256, 0, stream>>>(x, wk_w, wk_b, wv1_w, ln_g, ln_b, wv2_w,
                                    out, partial, attn, ctx, ovec, bar);
}